// Round 13
// baseline (328.852 us; speedup 1.0000x reference)
//
#include <hip/hip_runtime.h>
#include <math.h>

typedef __attribute__((ext_vector_type(8))) short short8;   // 8 bf16 in 4 VGPRs
typedef __attribute__((ext_vector_type(4))) float f32x4;

#define NCODE  1024
#define NDIM   256
#define TLEN   4096
#define NBATCH 16
#define BT     64
#define TAU    2.5e-2f

__device__ __forceinline__ unsigned short f2bf(float f) {
  unsigned int u = __float_as_uint(f);
  u += 0x7FFFu + ((u >> 16) & 1u);          // round-to-nearest-even
  return (unsigned short)(u >> 16);
}

// Codebook -> bf16 MFMA A-fragment order (+ tie-list counter reset).
// ushort index = ((ct*8 + ks)*64 + lane)*8 + j
// where row = ct*16 + (lane&15), k = ks*32 + (lane>>4)*8 + j
__global__ __launch_bounds__(256) void svq_prep_emb(const float* __restrict__ emb,
                                                    unsigned short* __restrict__ ehi,
                                                    unsigned int* __restrict__ ctr) {
  if (blockIdx.x == 0 && threadIdx.x == 0) *ctr = 0u;   // reset tie-list each launch
  int tid  = blockIdx.x * 256 + threadIdx.x;   // 0 .. 262143
  int j    = tid & 7;
  int lane = (tid >> 3) & 63;
  int blk  = tid >> 9;                          // ct*8 + ks
  int ct   = blk >> 3, ks = blk & 7;
  int row  = (ct << 4) | (lane & 15);
  int k    = (ks << 5) | ((lane >> 4) << 3) | j;
  ehi[tid] = f2bf(emb[row * NDIM + k]);
}

// Bit-exact tiled transpose emb[1024][256] -> embT[256][1024] (coalesced both
// sides; the old scattered embT write was ~25us of the prep cost).
__global__ __launch_bounds__(256) void svq_transpose(const float* __restrict__ emb,
                                                     float* __restrict__ embT) {
  __shared__ float tile[64][65];
  const int bc = blockIdx.x >> 2;        // code tile 0..15
  const int bd = blockIdx.x & 3;         // dim tile 0..3
  const int r0 = bc * 64, c0 = bd * 64;
  const int lc = threadIdx.x & 63;
  const int lr = threadIdx.x >> 6;       // 0..3
#pragma unroll
  for (int i = 0; i < 16; ++i) {
    int r = lr * 16 + i;
    tile[r][lc] = emb[(size_t)(r0 + r) * NDIM + c0 + lc];
  }
  __syncthreads();
#pragma unroll
  for (int i = 0; i < 16; ++i) {
    int c = lr * 16 + i;
    embT[(size_t)(c0 + c) * NCODE + r0 + lc] = tile[lc][c];
  }
}

// ===== svq_main: byte-for-byte the R9 version (PASSED, 80us) =====

// Accumulator pinned in AGPRs ("+a"): asm operands can't be spilled (the
// R4-R9 allocator pathology is structurally impossible). A/B in arch VGPRs.
#define MFMA_AGPR(ACC, A, B)                                                    \
  asm("v_mfma_f32_16x16x32_bf16 %0, %1, %2, %0" : "+a"(ACC) : "v"(A), "v"(B))

// One k-step, single-bf16, ci=4 blocking: 4 ds_read_b128 + 16 MFMA.
// A single-buffered, reloaded after the MFMAs. All indices compile-time
// constants (rule #20).
#define KSTEP(KS)                                                               \
  {                                                                             \
    const int kb0 = ((KS) * 32 + khalf) * 2;                                    \
    _Pragma("unroll")                                                           \
    for (int ti = 0; ti < 4; ++ti) {                                            \
      const int off = bbase + (kb0 ^ bswz) + ti * 8192;                         \
      short8 bh = *(const short8*)(xhi_s + off);                                \
      _Pragma("unroll")                                                         \
      for (int ci = 0; ci < 4; ++ci)                                            \
        MFMA_AGPR(acc[ci][ti], ah[ci], bh);                                     \
    }                                                                           \
    if ((KS) < 7) {                                                             \
      _Pragma("unroll")                                                         \
      for (int ci = 0; ci < 4; ++ci)                                            \
        ah[ci] = pe_h[(ci * 8 + (KS) + 1) * 64];                                \
    }                                                                           \
  }

// Arch live ~55 VGPRs + 64 AGPR acc = 128 total/wave -> 4 waves/EU.
__global__
__attribute__((amdgpu_flat_work_group_size(256, 256)))
__attribute__((amdgpu_waves_per_eu(4, 4)))
void svq_main(const float* __restrict__ x,
              const float* __restrict__ emb,
              const short8* __restrict__ ehi,
              float* __restrict__ out,
              unsigned int* __restrict__ ctr,
              int* __restrict__ list,
              int cap) {
  __shared__ char smem[32768];   // x_hi [64 t][512 B]; reused by reduce+epilogue
  const int tid  = threadIdx.x;
  const int lane = tid & 63;
  const int w    = tid >> 6;                 // wave id 0..3
  const int bx   = blockIdx.x;
  const int b    = bx >> 6;                  // batch
  const int t0   = (bx & 63) * BT;           // token-tile start

  // ---- stage x tile into LDS: bf16 hi, t-major rows of k, XOR bank swizzle ----
  {
    const float* xb = x + (size_t)b * NDIM * TLEN + t0;
    const int tl = lane;
    const int sw = (tl & 7) << 4;
#pragma unroll 4
    for (int it = 0; it < 16; ++it) {
      const int kb = w * 4 + it * 16;
      float v0 = xb[(size_t)(kb + 0) * TLEN + tl];
      float v1 = xb[(size_t)(kb + 1) * TLEN + tl];
      float v2 = xb[(size_t)(kb + 2) * TLEN + tl];
      float v3 = xb[(size_t)(kb + 3) * TLEN + tl];
      unsigned short h0 = f2bf(v0), h1 = f2bf(v1), h2 = f2bf(v2), h3 = f2bf(v3);
      unsigned long long ph = (unsigned long long)h0 | ((unsigned long long)h1 << 16)
                            | ((unsigned long long)h2 << 32) | ((unsigned long long)h3 << 48);
      *(unsigned long long*)(smem + tl * 512 + ((kb * 2) ^ sw)) = ph;
    }
  }
  __syncthreads();

  float bestv[4], secv[4];
  int   besti[4];
#pragma unroll
  for (int ti = 0; ti < 4; ++ti) {
    bestv[ti] = __builtin_inff(); secv[ti] = __builtin_inff(); besti[ti] = 0;
  }

  const char* xhi_s = smem;
  const int bbase = (lane & 15) * 512;        // t-row byte base (ti adds 8192)
  const int bswz  = (lane & 7) << 4;          // swizzle (ti*16 preserves t&7)
  const int khalf = (lane >> 4) << 3;         // k-subgroup within 32-k step

  // ---- main loop: wave w covers codes [w*256, w*256+256) in 4 chunks of 64 ----
  for (int cc = 0; cc < 4; ++cc) {
    const int ctb = w * 16 + cc * 4;          // base 16-code tile index
    const short8* pe_h = ehi + (size_t)ctb * 8 * 64 + lane;

    f32x4 acc[4][4];
#pragma unroll
    for (int ci = 0; ci < 4; ++ci)
#pragma unroll
      for (int ti = 0; ti < 4; ++ti)
        acc[ci][ti] = (f32x4){0.f, 0.f, 0.f, 0.f};

    short8 ah[4];
#pragma unroll
    for (int ci = 0; ci < 4; ++ci) ah[ci] = pe_h[ci * 8 * 64];

    asm volatile("s_nop 1");   // VALU-write-AGPR -> MFMA-read-C wait states

    KSTEP(0) KSTEP(1) KSTEP(2) KSTEP(3)
    KSTEP(4) KSTEP(5) KSTEP(6) KSTEP(7)

    // MFMA-write-AGPR -> VALU(accvgpr_read) wait states
    asm volatile("s_nop 7\n\ts_nop 7\n\ts_nop 7");

    // best + second-best of eu = 2 - 2*dot, ascending code order per lane
#pragma unroll
    for (int ci = 0; ci < 4; ++ci) {
      const int cbase = (ctb + ci) * 16 + ((lane >> 4) << 2);
#pragma unroll
      for (int j = 0; j < 4; ++j) {
#pragma unroll
        for (int ti = 0; ti < 4; ++ti) {
          float eu = fmaf(-2.0f, acc[ci][ti][j], 2.0f);
          if (eu < bestv[ti])      { secv[ti] = bestv[ti]; bestv[ti] = eu; besti[ti] = cbase + j; }
          else if (eu < secv[ti])  { secv[ti] = eu; }
        }
      }
    }
  }

  __syncthreads();   // all waves done with x LDS; reuse region below

  float* red_v = (float*)smem;
  float* red_s = (float*)(smem + 1024);
  int*   red_i = (int*)(smem + 2048);
  int*   idxf  = (int*)(smem + 3072);

  // cross-lane reduce, merging (best, second), tie-break lower index
#pragma unroll
  for (int ti = 0; ti < 4; ++ti) {
    float v = bestv[ti], s = secv[ti]; int ix = besti[ti];
#pragma unroll
    for (int off = 16; off < 64; off <<= 1) {
      float ov = __shfl_xor(v, off);
      float os = __shfl_xor(s, off);
      int   oi = __shfl_xor(ix, off);
      if (ov < v || (ov == v && oi < ix)) { s = fminf(v, os); v = ov; ix = oi; }
      else                                { s = fminf(s, ov); }
    }
    if (lane < 16) {
      red_v[w * 64 + ti * 16 + lane] = v;
      red_s[w * 64 + ti * 16 + lane] = s;
      red_i[w * 64 + ti * 16 + lane] = ix;
    }
  }
  __syncthreads();
  if (tid < 64) {       // cross-wave reduce
    float v = red_v[tid], s = red_s[tid]; int ix = red_i[tid];
#pragma unroll
    for (int ww = 1; ww < 4; ++ww) {
      float ov = red_v[ww * 64 + tid], os = red_s[ww * 64 + tid];
      int   oi = red_i[ww * 64 + tid];
      if (ov < v || (ov == v && oi < ix)) { s = fminf(v, os); v = ov; ix = oi; }
      else                                { s = fminf(s, ov); }
    }
    idxf[tid] = ix;
    if (s - v < TAU) {   // near-tie: np-bit-replicated rescore will overwrite this token
      unsigned int slot = atomicAdd(ctr, 1u);
      if ((int)slot < cap) list[slot] = (b << 12) | (t0 + tid);
    }
  }
  __syncthreads();

  // ---- epilogue: winning emb rows via LDS (rotated), 2 dim-halves of 128 ----
  const int rt = tid >> 2, q = tid & 3;      // rt = token 0..63, q = quarter
  const int code = idxf[rt];
  __syncthreads();     // everyone has its code; safe to overwrite smem

  float* rows = (float*)smem;   // [64][128] f32, column rotated by +rt
  const float4* src = (const float4*)(emb + (size_t)code * NDIM);
  for (int h = 0; h < 2; ++h) {
#pragma unroll
    for (int i = 0; i < 8; ++i) {
      float4 v = src[h * 32 + q + 4 * i];
      int n = 4 * (q + 4 * i);               // 0..127 within half
      rows[rt * 128 + ((n + 0 + rt) & 127)] = v.x;
      rows[rt * 128 + ((n + 1 + rt) & 127)] = v.y;
      rows[rt * 128 + ((n + 2 + rt) & 127)] = v.z;
      rows[rt * 128 + ((n + 3 + rt) & 127)] = v.w;
    }
    __syncthreads();
    {
      float* op = out + (size_t)b * NDIM * TLEN + (size_t)h * 128 * TLEN + t0 + lane;
#pragma unroll 8
      for (int i = 0; i < 32; ++i) {
        int n = w * 32 + i;                  // 0..127 within half
        op[(size_t)n * TLEN] = rows[lane * 128 + ((n + lane) & 127)];
      }
    }
    __syncthreads();
  }
}

// Rescore near-tied tokens, BIT-REPLICATING the numpy fp32 reference:
// per (code, token) a SEQUENTIAL fp32 FMA chain over k ascending, then
// eu = 2.0f - 2.0f*acc, argmin first-min-wins. 16 tokens/block (bisect
// variable under test this round); embT gives coalesced loads.
__global__
__attribute__((amdgpu_flat_work_group_size(256, 256)))
__attribute__((amdgpu_waves_per_eu(4, 4)))
void svq_rescore(const float* __restrict__ x,
                 const float* __restrict__ emb,
                 const float* __restrict__ embT,
                 float* __restrict__ out,
                 const unsigned int* __restrict__ ctr,
                 const int* __restrict__ list,
                 int cap) {
  __shared__ float xs[16][256];
  __shared__ int   toks[16];
  __shared__ float rv[16][4];
  __shared__ int   ri[16][4];
  __shared__ int   widx[16];
  const int tid  = threadIdx.x;
  const int lane = tid & 63;
  const int w    = tid >> 6;
  int n = (int)*ctr;
  if (n > cap) n = cap;
  const int nb = (n + 15) >> 4;
  for (int bb = blockIdx.x; bb < nb; bb += gridDim.x) {
    const int base = bb << 4;
    const int m = (n - base) < 16 ? (n - base) : 16;   // block-uniform, >=1
    if (tid < 16) toks[tid] = list[base + (tid < m ? tid : (m - 1))];
    __syncthreads();
#pragma unroll
    for (int tt = 0; tt < 16; ++tt) {
      int tok = toks[tt];
      xs[tt][tid] = x[(size_t)(tok >> 12) * NDIM * TLEN + (size_t)tid * TLEN + (tok & (TLEN - 1))];
    }
    __syncthreads();

    float a[4][16];
#pragma unroll
    for (int c4 = 0; c4 < 4; ++c4)
#pragma unroll
      for (int tt = 0; tt < 16; ++tt) a[c4][tt] = 0.0f;

#pragma unroll 2
    for (int k = 0; k < NDIM; ++k) {
#pragma unroll
      for (int c4 = 0; c4 < 4; ++c4) {
        float ev = embT[(size_t)k * NCODE + c4 * 256 + tid];
#pragma unroll
        for (int tt = 0; tt < 16; ++tt) a[c4][tt] = fmaf(xs[tt][k], ev, a[c4][tt]);
      }
    }

#pragma unroll
    for (int tt = 0; tt < 16; ++tt) {
      float bt = __builtin_inff(); int bi = 0;
#pragma unroll
      for (int c4 = 0; c4 < 4; ++c4) {       // ascending c4 = ascending code
        float eu = 2.0f - 2.0f * a[c4][tt];
        if (eu < bt) { bt = eu; bi = c4 * 256 + tid; }
      }
      float v = bt; int ix = bi;
#pragma unroll
      for (int off = 32; off >= 1; off >>= 1) {
        float ov = __shfl_xor(v, off);
        int   oi = __shfl_xor(ix, off);
        if (ov < v || (ov == v && oi < ix)) { v = ov; ix = oi; }
      }
      if (lane == 0) { rv[tt][w] = v; ri[tt][w] = ix; }
    }
    __syncthreads();
    if (tid < 16) {
      float v = rv[tid][0]; int ix = ri[tid][0];
#pragma unroll
      for (int ww = 1; ww < 4; ++ww) {
        float ov = rv[tid][ww]; int oi = ri[tid][ww];
        if (ov < v || (ov == v && oi < ix)) { v = ov; ix = oi; }
      }
      widx[tid] = ix;
    }
    __syncthreads();
#pragma unroll
    for (int tt = 0; tt < 16; ++tt) {
      if (tt < m) {
        int tok = toks[tt];
        out[(size_t)(tok >> 12) * NDIM * TLEN + (size_t)tid * TLEN + (tok & (TLEN - 1))] =
            emb[(size_t)widx[tt] * NDIM + tid];
      }
    }
    __syncthreads();   // before next iteration overwrites xs/rv/ri/widx
  }
}

extern "C" void kernel_launch(void* const* d_in, const int* in_sizes, int n_in,
                              void* d_out, int out_size, void* d_ws, size_t ws_size,
                              hipStream_t stream) {
  (void)in_sizes; (void)n_in; (void)out_size;
  const float* x   = (const float*)d_in[0];
  const float* emb = (const float*)d_in[1];
  float* out = (float*)d_out;

  // ws layout: ehi 512KB | embT 1MB | ctr 16B | list
  unsigned short* ehi  = (unsigned short*)d_ws;
  float*          embT = (float*)((char*)d_ws + (size_t)512 * 1024);
  unsigned int*   ctr  = (unsigned int*)((char*)d_ws + (size_t)1536 * 1024);
  int*            lst  = (int*)((char*)ctr + 16);

  long avail = (long)ws_size - (long)1536 * 1024 - 16;
  int cap = avail > 0 ? (int)(avail / 4 < 65536 ? avail / 4 : 65536) : 0;

  svq_prep_emb<<<dim3(1024), dim3(256), 0, stream>>>(emb, ehi, ctr);
  svq_transpose<<<dim3(64), dim3(256), 0, stream>>>(emb, embT);
  svq_main<<<dim3(NBATCH * (TLEN / BT)), dim3(256), 0, stream>>>(
      x, emb, (const short8*)ehi, out, ctr, lst, cap);
  svq_rescore<<<dim3(1024), dim3(256), 0, stream>>>(x, emb, embT, out, ctr, lst, cap);
}

// Round 14
// 187.792 us; speedup vs baseline: 1.7511x; 1.7511x over previous
//
#include <hip/hip_runtime.h>
#include <math.h>

typedef __attribute__((ext_vector_type(8))) short short8;   // 8 bf16 in 4 VGPRs
typedef __attribute__((ext_vector_type(4))) float f32x4;

#define NCODE  1024
#define NDIM   256
#define TLEN   4096
#define NBATCH 16
#define BT     64
#define TAU    2.5e-2f

__device__ __forceinline__ unsigned short f2bf(float f) {
  unsigned int u = __float_as_uint(f);
  u += 0x7FFFu + ((u >> 16) & 1u);          // round-to-nearest-even
  return (unsigned short)(u >> 16);
}

// Codebook -> bf16 MFMA A-fragment order (+ tie-list counter reset).
// ushort index = ((ct*8 + ks)*64 + lane)*8 + j
// where row = ct*16 + (lane&15), k = ks*32 + (lane>>4)*8 + j
__global__ __launch_bounds__(256) void svq_prep_emb(const float* __restrict__ emb,
                                                    unsigned short* __restrict__ ehi,
                                                    unsigned int* __restrict__ ctr) {
  if (blockIdx.x == 0 && threadIdx.x == 0) *ctr = 0u;   // reset tie-list each launch
  int tid  = blockIdx.x * 256 + threadIdx.x;   // 0 .. 262143
  int j    = tid & 7;
  int lane = (tid >> 3) & 63;
  int blk  = tid >> 9;                          // ct*8 + ks
  int ct   = blk >> 3, ks = blk & 7;
  int row  = (ct << 4) | (lane & 15);
  int k    = (ks << 5) | ((lane >> 4) << 3) | j;
  ehi[tid] = f2bf(emb[row * NDIM + k]);
}

// Bit-exact tiled transpose emb[1024][256] -> embT[256][1024].
__global__ __launch_bounds__(256) void svq_transpose(const float* __restrict__ emb,
                                                     float* __restrict__ embT) {
  __shared__ float tile[64][65];
  const int bc = blockIdx.x >> 2;        // code tile 0..15
  const int bd = blockIdx.x & 3;         // dim tile 0..3
  const int r0 = bc * 64, c0 = bd * 64;
  const int lc = threadIdx.x & 63;
  const int lr = threadIdx.x >> 6;       // 0..3
#pragma unroll
  for (int i = 0; i < 16; ++i) {
    int r = lr * 16 + i;
    tile[r][lc] = emb[(size_t)(r0 + r) * NDIM + c0 + lc];
  }
  __syncthreads();
#pragma unroll
  for (int i = 0; i < 16; ++i) {
    int c = lr * 16 + i;
    embT[(size_t)(c0 + c) * NCODE + r0 + lc] = tile[lc][c];
  }
}

// ===== svq_main: byte-for-byte the R9/R13 version (PASSED twice, ~80us) =====

// Accumulator pinned in AGPRs ("+a"): asm operands can't be spilled (the
// R4-R9 allocator pathology is structurally impossible). A/B in arch VGPRs.
#define MFMA_AGPR(ACC, A, B)                                                    \
  asm("v_mfma_f32_16x16x32_bf16 %0, %1, %2, %0" : "+a"(ACC) : "v"(A), "v"(B))

// One k-step, single-bf16, ci=4 blocking: 4 ds_read_b128 + 16 MFMA.
// A single-buffered, reloaded after the MFMAs. All indices compile-time
// constants (rule #20).
#define KSTEP(KS)                                                               \
  {                                                                             \
    const int kb0 = ((KS) * 32 + khalf) * 2;                                    \
    _Pragma("unroll")                                                           \
    for (int ti = 0; ti < 4; ++ti) {                                            \
      const int off = bbase + (kb0 ^ bswz) + ti * 8192;                         \
      short8 bh = *(const short8*)(xhi_s + off);                                \
      _Pragma("unroll")                                                         \
      for (int ci = 0; ci < 4; ++ci)                                            \
        MFMA_AGPR(acc[ci][ti], ah[ci], bh);                                     \
    }                                                                           \
    if ((KS) < 7) {                                                             \
      _Pragma("unroll")                                                         \
      for (int ci = 0; ci < 4; ++ci)                                            \
        ah[ci] = pe_h[(ci * 8 + (KS) + 1) * 64];                                \
    }                                                                           \
  }

// Arch live ~55 VGPRs + 64 AGPR acc = 128 total/wave -> 4 waves/EU.
__global__
__attribute__((amdgpu_flat_work_group_size(256, 256)))
__attribute__((amdgpu_waves_per_eu(4, 4)))
void svq_main(const float* __restrict__ x,
              const float* __restrict__ emb,
              const short8* __restrict__ ehi,
              float* __restrict__ out,
              unsigned int* __restrict__ ctr,
              int* __restrict__ list,
              int cap) {
  __shared__ char smem[32768];   // x_hi [64 t][512 B]; reused by reduce+epilogue
  const int tid  = threadIdx.x;
  const int lane = tid & 63;
  const int w    = tid >> 6;                 // wave id 0..3
  const int bx   = blockIdx.x;
  const int b    = bx >> 6;                  // batch
  const int t0   = (bx & 63) * BT;           // token-tile start

  // ---- stage x tile into LDS: bf16 hi, t-major rows of k, XOR bank swizzle ----
  {
    const float* xb = x + (size_t)b * NDIM * TLEN + t0;
    const int tl = lane;
    const int sw = (tl & 7) << 4;
#pragma unroll 4
    for (int it = 0; it < 16; ++it) {
      const int kb = w * 4 + it * 16;
      float v0 = xb[(size_t)(kb + 0) * TLEN + tl];
      float v1 = xb[(size_t)(kb + 1) * TLEN + tl];
      float v2 = xb[(size_t)(kb + 2) * TLEN + tl];
      float v3 = xb[(size_t)(kb + 3) * TLEN + tl];
      unsigned short h0 = f2bf(v0), h1 = f2bf(v1), h2 = f2bf(v2), h3 = f2bf(v3);
      unsigned long long ph = (unsigned long long)h0 | ((unsigned long long)h1 << 16)
                            | ((unsigned long long)h2 << 32) | ((unsigned long long)h3 << 48);
      *(unsigned long long*)(smem + tl * 512 + ((kb * 2) ^ sw)) = ph;
    }
  }
  __syncthreads();

  float bestv[4], secv[4];
  int   besti[4];
#pragma unroll
  for (int ti = 0; ti < 4; ++ti) {
    bestv[ti] = __builtin_inff(); secv[ti] = __builtin_inff(); besti[ti] = 0;
  }

  const char* xhi_s = smem;
  const int bbase = (lane & 15) * 512;        // t-row byte base (ti adds 8192)
  const int bswz  = (lane & 7) << 4;          // swizzle (ti*16 preserves t&7)
  const int khalf = (lane >> 4) << 3;         // k-subgroup within 32-k step

  // ---- main loop: wave w covers codes [w*256, w*256+256) in 4 chunks of 64 ----
  for (int cc = 0; cc < 4; ++cc) {
    const int ctb = w * 16 + cc * 4;          // base 16-code tile index
    const short8* pe_h = ehi + (size_t)ctb * 8 * 64 + lane;

    f32x4 acc[4][4];
#pragma unroll
    for (int ci = 0; ci < 4; ++ci)
#pragma unroll
      for (int ti = 0; ti < 4; ++ti)
        acc[ci][ti] = (f32x4){0.f, 0.f, 0.f, 0.f};

    short8 ah[4];
#pragma unroll
    for (int ci = 0; ci < 4; ++ci) ah[ci] = pe_h[ci * 8 * 64];

    asm volatile("s_nop 1");   // VALU-write-AGPR -> MFMA-read-C wait states

    KSTEP(0) KSTEP(1) KSTEP(2) KSTEP(3)
    KSTEP(4) KSTEP(5) KSTEP(6) KSTEP(7)

    // MFMA-write-AGPR -> VALU(accvgpr_read) wait states
    asm volatile("s_nop 7\n\ts_nop 7\n\ts_nop 7");

    // best + second-best of eu = 2 - 2*dot, ascending code order per lane
#pragma unroll
    for (int ci = 0; ci < 4; ++ci) {
      const int cbase = (ctb + ci) * 16 + ((lane >> 4) << 2);
#pragma unroll
      for (int j = 0; j < 4; ++j) {
#pragma unroll
        for (int ti = 0; ti < 4; ++ti) {
          float eu = fmaf(-2.0f, acc[ci][ti][j], 2.0f);
          if (eu < bestv[ti])      { secv[ti] = bestv[ti]; bestv[ti] = eu; besti[ti] = cbase + j; }
          else if (eu < secv[ti])  { secv[ti] = eu; }
        }
      }
    }
  }

  __syncthreads();   // all waves done with x LDS; reuse region below

  float* red_v = (float*)smem;
  float* red_s = (float*)(smem + 1024);
  int*   red_i = (int*)(smem + 2048);
  int*   idxf  = (int*)(smem + 3072);

  // cross-lane reduce, merging (best, second), tie-break lower index
#pragma unroll
  for (int ti = 0; ti < 4; ++ti) {
    float v = bestv[ti], s = secv[ti]; int ix = besti[ti];
#pragma unroll
    for (int off = 16; off < 64; off <<= 1) {
      float ov = __shfl_xor(v, off);
      float os = __shfl_xor(s, off);
      int   oi = __shfl_xor(ix, off);
      if (ov < v || (ov == v && oi < ix)) { s = fminf(v, os); v = ov; ix = oi; }
      else                                { s = fminf(s, ov); }
    }
    if (lane < 16) {
      red_v[w * 64 + ti * 16 + lane] = v;
      red_s[w * 64 + ti * 16 + lane] = s;
      red_i[w * 64 + ti * 16 + lane] = ix;
    }
  }
  __syncthreads();
  if (tid < 64) {       // cross-wave reduce
    float v = red_v[tid], s = red_s[tid]; int ix = red_i[tid];
#pragma unroll
    for (int ww = 1; ww < 4; ++ww) {
      float ov = red_v[ww * 64 + tid], os = red_s[ww * 64 + tid];
      int   oi = red_i[ww * 64 + tid];
      if (ov < v || (ov == v && oi < ix)) { s = fminf(v, os); v = ov; ix = oi; }
      else                                { s = fminf(s, ov); }
    }
    idxf[tid] = ix;
    if (s - v < TAU) {   // near-tie: np-bit-replicated rescore will overwrite this token
      unsigned int slot = atomicAdd(ctr, 1u);
      if ((int)slot < cap) list[slot] = (b << 12) | (t0 + tid);
    }
  }
  __syncthreads();

  // ---- epilogue: winning emb rows via LDS (rotated), 2 dim-halves of 128 ----
  const int rt = tid >> 2, q = tid & 3;      // rt = token 0..63, q = quarter
  const int code = idxf[rt];
  __syncthreads();     // everyone has its code; safe to overwrite smem

  float* rows = (float*)smem;   // [64][128] f32, column rotated by +rt
  const float4* src = (const float4*)(emb + (size_t)code * NDIM);
  for (int h = 0; h < 2; ++h) {
#pragma unroll
    for (int i = 0; i < 8; ++i) {
      float4 v = src[h * 32 + q + 4 * i];
      int n = 4 * (q + 4 * i);               // 0..127 within half
      rows[rt * 128 + ((n + 0 + rt) & 127)] = v.x;
      rows[rt * 128 + ((n + 1 + rt) & 127)] = v.y;
      rows[rt * 128 + ((n + 2 + rt) & 127)] = v.z;
      rows[rt * 128 + ((n + 3 + rt) & 127)] = v.w;
    }
    __syncthreads();
    {
      float* op = out + (size_t)b * NDIM * TLEN + (size_t)h * 128 * TLEN + t0 + lane;
#pragma unroll 8
      for (int i = 0; i < 32; ++i) {
        int n = w * 32 + i;                  // 0..127 within half
        op[(size_t)n * TLEN] = rows[lane * 128 + ((n + lane) & 127)];
      }
    }
    __syncthreads();
  }
}

// Rescore near-tied tokens, BIT-REPLICATING the numpy fp32 reference:
// per (code, token) a SEQUENTIAL fp32 FMA chain over k ascending, then
// eu = 2.0f - 2.0f*acc, argmin first-min-wins (validated R3/R10/R13).
// v4: c4-OUTER loop so only a[8] accumulators are live (~35 VGPRs total) —
// R13's a[4][16] spilled at the allocator's 64-reg choice and cost 252us.
// Chain order per (code, token) is unchanged (k ascending) -> bit-identical.
__global__
__attribute__((amdgpu_flat_work_group_size(256, 256)))
void svq_rescore(const float* __restrict__ x,
                 const float* __restrict__ emb,
                 const float* __restrict__ embT,
                 float* __restrict__ out,
                 const unsigned int* __restrict__ ctr,
                 const int* __restrict__ list,
                 int cap) {
  __shared__ float xs[8][256];
  __shared__ int   toks[8];
  __shared__ float rv[8][4];
  __shared__ int   ri[8][4];
  __shared__ int   widx[8];
  const int tid  = threadIdx.x;
  const int lane = tid & 63;
  const int w    = tid >> 6;
  int n = (int)*ctr;
  if (n > cap) n = cap;
  const int nb = (n + 7) >> 3;
  for (int bb = blockIdx.x; bb < nb; bb += gridDim.x) {
    const int base = bb << 3;
    const int m = (n - base) < 8 ? (n - base) : 8;   // block-uniform, >=1
    if (tid < 8) toks[tid] = list[base + (tid < m ? tid : (m - 1))];
    __syncthreads();
#pragma unroll
    for (int tt = 0; tt < 8; ++tt) {
      int tok = toks[tt];
      xs[tt][tid] = x[(size_t)(tok >> 12) * NDIM * TLEN + (size_t)tid * TLEN + (tok & (TLEN - 1))];
    }
    __syncthreads();

    float bt[8]; int bi[8];
#pragma unroll
    for (int tt = 0; tt < 8; ++tt) { bt[tt] = __builtin_inff(); bi[tt] = 0; }

    for (int c4 = 0; c4 < 4; ++c4) {         // ascending c4 = ascending code
      float a[8];
#pragma unroll
      for (int tt = 0; tt < 8; ++tt) a[tt] = 0.0f;
#pragma unroll 4
      for (int k = 0; k < NDIM; ++k) {
        float ev = embT[(size_t)k * NCODE + c4 * 256 + tid];
#pragma unroll
        for (int tt = 0; tt < 8; ++tt) a[tt] = fmaf(xs[tt][k], ev, a[tt]);
      }
#pragma unroll
      for (int tt = 0; tt < 8; ++tt) {
        float eu = 2.0f - 2.0f * a[tt];
        if (eu < bt[tt]) { bt[tt] = eu; bi[tt] = c4 * 256 + tid; }
      }
    }

    // in-wave min+index reduce per token, then cross-wave via LDS
#pragma unroll
    for (int tt = 0; tt < 8; ++tt) {
      float v = bt[tt]; int ix = bi[tt];
#pragma unroll
      for (int off = 32; off >= 1; off >>= 1) {
        float ov = __shfl_xor(v, off);
        int   oi = __shfl_xor(ix, off);
        if (ov < v || (ov == v && oi < ix)) { v = ov; ix = oi; }
      }
      if (lane == 0) { rv[tt][w] = v; ri[tt][w] = ix; }
    }
    __syncthreads();
    if (tid < 8) {
      float v = rv[tid][0]; int ix = ri[tid][0];
#pragma unroll
      for (int ww = 1; ww < 4; ++ww) {
        float ov = rv[tid][ww]; int oi = ri[tid][ww];
        if (ov < v || (ov == v && oi < ix)) { v = ov; ix = oi; }
      }
      widx[tid] = ix;
    }
    __syncthreads();
#pragma unroll
    for (int tt = 0; tt < 8; ++tt) {
      if (tt < m) {
        int tok = toks[tt];
        out[(size_t)(tok >> 12) * NDIM * TLEN + (size_t)tid * TLEN + (tok & (TLEN - 1))] =
            emb[(size_t)widx[tt] * NDIM + tid];
      }
    }
    __syncthreads();   // before next iteration overwrites xs/rv/ri/widx
  }
}

extern "C" void kernel_launch(void* const* d_in, const int* in_sizes, int n_in,
                              void* d_out, int out_size, void* d_ws, size_t ws_size,
                              hipStream_t stream) {
  (void)in_sizes; (void)n_in; (void)out_size;
  const float* x   = (const float*)d_in[0];
  const float* emb = (const float*)d_in[1];
  float* out = (float*)d_out;

  // ws layout: ehi 512KB | embT 1MB | ctr 16B | list
  unsigned short* ehi  = (unsigned short*)d_ws;
  float*          embT = (float*)((char*)d_ws + (size_t)512 * 1024);
  unsigned int*   ctr  = (unsigned int*)((char*)d_ws + (size_t)1536 * 1024);
  int*            lst  = (int*)((char*)ctr + 16);

  long avail = (long)ws_size - (long)1536 * 1024 - 16;
  int cap = avail > 0 ? (int)(avail / 4 < 65536 ? avail / 4 : 65536) : 0;

  svq_prep_emb<<<dim3(1024), dim3(256), 0, stream>>>(emb, ehi, ctr);
  svq_transpose<<<dim3(64), dim3(256), 0, stream>>>(emb, embT);
  svq_main<<<dim3(NBATCH * (TLEN / BT)), dim3(256), 0, stream>>>(
      x, emb, (const short8*)ehi, out, ctr, lst, cap);
  svq_rescore<<<dim3(512), dim3(256), 0, stream>>>(x, emb, embT, out, ctr, lst, cap);
}

// Round 15
// 160.398 us; speedup vs baseline: 2.0502x; 1.1708x over previous
//
#include <hip/hip_runtime.h>
#include <math.h>

typedef __attribute__((ext_vector_type(8))) short short8;   // 8 bf16 in 4 VGPRs
typedef __attribute__((ext_vector_type(4))) float f32x4;

#define NCODE  1024
#define NDIM   256
#define TLEN   4096
#define NBATCH 16
#define BT     64
#define TAU    2.5e-2f

__device__ __forceinline__ unsigned short f2bf(float f) {
  unsigned int u = __float_as_uint(f);
  u += 0x7FFFu + ((u >> 16) & 1u);          // round-to-nearest-even
  return (unsigned short)(u >> 16);
}

// Ordered-monotone encoding of float for u64 atomicMin (min eu, then min idx).
__device__ __forceinline__ unsigned int ordf(float f) {
  unsigned int u = __float_as_uint(f);
  return (u & 0x80000000u) ? ~u : (u | 0x80000000u);
}

// Codebook -> bf16 MFMA A-fragment order; reset tie counter; init tokmin.
__global__ __launch_bounds__(256) void svq_prep_emb(const float* __restrict__ emb,
                                                    unsigned short* __restrict__ ehi,
                                                    unsigned int* __restrict__ ctr,
                                                    unsigned long long* __restrict__ tokmin,
                                                    int cap) {
  int gtid = blockIdx.x * 256 + threadIdx.x;
  if (gtid == 0) *ctr = 0u;
  if (gtid < cap) tokmin[gtid] = ~0ull;
  int tid  = gtid;                              // 0 .. 262143
  int j    = tid & 7;
  int lane = (tid >> 3) & 63;
  int blk  = tid >> 9;                          // ct*8 + ks
  int ct   = blk >> 3, ks = blk & 7;
  int row  = (ct << 4) | (lane & 15);
  int k    = (ks << 5) | ((lane >> 4) << 3) | j;
  ehi[tid] = f2bf(emb[row * NDIM + k]);
}

// Bit-exact tiled transpose emb[1024][256] -> embT[256][1024].
__global__ __launch_bounds__(256) void svq_transpose(const float* __restrict__ emb,
                                                     float* __restrict__ embT) {
  __shared__ float tile[64][65];
  const int bc = blockIdx.x >> 2;        // code tile 0..15
  const int bd = blockIdx.x & 3;         // dim tile 0..3
  const int r0 = bc * 64, c0 = bd * 64;
  const int lc = threadIdx.x & 63;
  const int lr = threadIdx.x >> 6;       // 0..3
#pragma unroll
  for (int i = 0; i < 16; ++i) {
    int r = lr * 16 + i;
    tile[r][lc] = emb[(size_t)(r0 + r) * NDIM + c0 + lc];
  }
  __syncthreads();
#pragma unroll
  for (int i = 0; i < 16; ++i) {
    int c = lr * 16 + i;
    embT[(size_t)(c0 + c) * NCODE + r0 + lc] = tile[lc][c];
  }
}

// ===== svq_main: byte-for-byte the R9/R13/R14 version (PASSED 3x, ~80us) =====

#define MFMA_AGPR(ACC, A, B)                                                    \
  asm("v_mfma_f32_16x16x32_bf16 %0, %1, %2, %0" : "+a"(ACC) : "v"(A), "v"(B))

#define KSTEP(KS)                                                               \
  {                                                                             \
    const int kb0 = ((KS) * 32 + khalf) * 2;                                    \
    _Pragma("unroll")                                                           \
    for (int ti = 0; ti < 4; ++ti) {                                            \
      const int off = bbase + (kb0 ^ bswz) + ti * 8192;                         \
      short8 bh = *(const short8*)(xhi_s + off);                                \
      _Pragma("unroll")                                                         \
      for (int ci = 0; ci < 4; ++ci)                                            \
        MFMA_AGPR(acc[ci][ti], ah[ci], bh);                                     \
    }                                                                           \
    if ((KS) < 7) {                                                             \
      _Pragma("unroll")                                                         \
      for (int ci = 0; ci < 4; ++ci)                                            \
        ah[ci] = pe_h[(ci * 8 + (KS) + 1) * 64];                                \
    }                                                                           \
  }

__global__
__attribute__((amdgpu_flat_work_group_size(256, 256)))
__attribute__((amdgpu_waves_per_eu(4, 4)))
void svq_main(const float* __restrict__ x,
              const float* __restrict__ emb,
              const short8* __restrict__ ehi,
              float* __restrict__ out,
              unsigned int* __restrict__ ctr,
              int* __restrict__ list,
              int cap) {
  __shared__ char smem[32768];   // x_hi [64 t][512 B]; reused by reduce+epilogue
  const int tid  = threadIdx.x;
  const int lane = tid & 63;
  const int w    = tid >> 6;                 // wave id 0..3
  const int bx   = blockIdx.x;
  const int b    = bx >> 6;                  // batch
  const int t0   = (bx & 63) * BT;           // token-tile start

  {
    const float* xb = x + (size_t)b * NDIM * TLEN + t0;
    const int tl = lane;
    const int sw = (tl & 7) << 4;
#pragma unroll 4
    for (int it = 0; it < 16; ++it) {
      const int kb = w * 4 + it * 16;
      float v0 = xb[(size_t)(kb + 0) * TLEN + tl];
      float v1 = xb[(size_t)(kb + 1) * TLEN + tl];
      float v2 = xb[(size_t)(kb + 2) * TLEN + tl];
      float v3 = xb[(size_t)(kb + 3) * TLEN + tl];
      unsigned short h0 = f2bf(v0), h1 = f2bf(v1), h2 = f2bf(v2), h3 = f2bf(v3);
      unsigned long long ph = (unsigned long long)h0 | ((unsigned long long)h1 << 16)
                            | ((unsigned long long)h2 << 32) | ((unsigned long long)h3 << 48);
      *(unsigned long long*)(smem + tl * 512 + ((kb * 2) ^ sw)) = ph;
    }
  }
  __syncthreads();

  float bestv[4], secv[4];
  int   besti[4];
#pragma unroll
  for (int ti = 0; ti < 4; ++ti) {
    bestv[ti] = __builtin_inff(); secv[ti] = __builtin_inff(); besti[ti] = 0;
  }

  const char* xhi_s = smem;
  const int bbase = (lane & 15) * 512;
  const int bswz  = (lane & 7) << 4;
  const int khalf = (lane >> 4) << 3;

  for (int cc = 0; cc < 4; ++cc) {
    const int ctb = w * 16 + cc * 4;
    const short8* pe_h = ehi + (size_t)ctb * 8 * 64 + lane;

    f32x4 acc[4][4];
#pragma unroll
    for (int ci = 0; ci < 4; ++ci)
#pragma unroll
      for (int ti = 0; ti < 4; ++ti)
        acc[ci][ti] = (f32x4){0.f, 0.f, 0.f, 0.f};

    short8 ah[4];
#pragma unroll
    for (int ci = 0; ci < 4; ++ci) ah[ci] = pe_h[ci * 8 * 64];

    asm volatile("s_nop 1");

    KSTEP(0) KSTEP(1) KSTEP(2) KSTEP(3)
    KSTEP(4) KSTEP(5) KSTEP(6) KSTEP(7)

    asm volatile("s_nop 7\n\ts_nop 7\n\ts_nop 7");

#pragma unroll
    for (int ci = 0; ci < 4; ++ci) {
      const int cbase = (ctb + ci) * 16 + ((lane >> 4) << 2);
#pragma unroll
      for (int j = 0; j < 4; ++j) {
#pragma unroll
        for (int ti = 0; ti < 4; ++ti) {
          float eu = fmaf(-2.0f, acc[ci][ti][j], 2.0f);
          if (eu < bestv[ti])      { secv[ti] = bestv[ti]; bestv[ti] = eu; besti[ti] = cbase + j; }
          else if (eu < secv[ti])  { secv[ti] = eu; }
        }
      }
    }
  }

  __syncthreads();

  float* red_v = (float*)smem;
  float* red_s = (float*)(smem + 1024);
  int*   red_i = (int*)(smem + 2048);
  int*   idxf  = (int*)(smem + 3072);

#pragma unroll
  for (int ti = 0; ti < 4; ++ti) {
    float v = bestv[ti], s = secv[ti]; int ix = besti[ti];
#pragma unroll
    for (int off = 16; off < 64; off <<= 1) {
      float ov = __shfl_xor(v, off);
      float os = __shfl_xor(s, off);
      int   oi = __shfl_xor(ix, off);
      if (ov < v || (ov == v && oi < ix)) { s = fminf(v, os); v = ov; ix = oi; }
      else                                { s = fminf(s, ov); }
    }
    if (lane < 16) {
      red_v[w * 64 + ti * 16 + lane] = v;
      red_s[w * 64 + ti * 16 + lane] = s;
      red_i[w * 64 + ti * 16 + lane] = ix;
    }
  }
  __syncthreads();
  if (tid < 64) {
    float v = red_v[tid], s = red_s[tid]; int ix = red_i[tid];
#pragma unroll
    for (int ww = 1; ww < 4; ++ww) {
      float ov = red_v[ww * 64 + tid], os = red_s[ww * 64 + tid];
      int   oi = red_i[ww * 64 + tid];
      if (ov < v || (ov == v && oi < ix)) { s = fminf(v, os); v = ov; ix = oi; }
      else                                { s = fminf(s, ov); }
    }
    idxf[tid] = ix;
    if (s - v < TAU) {
      unsigned int slot = atomicAdd(ctr, 1u);
      if ((int)slot < cap) list[slot] = (b << 12) | (t0 + tid);
    }
  }
  __syncthreads();

  const int rt = tid >> 2, q = tid & 3;
  const int code = idxf[rt];
  __syncthreads();

  float* rows = (float*)smem;
  const float4* src = (const float4*)(emb + (size_t)code * NDIM);
  for (int h = 0; h < 2; ++h) {
#pragma unroll
    for (int i = 0; i < 8; ++i) {
      float4 v = src[h * 32 + q + 4 * i];
      int n = 4 * (q + 4 * i);
      rows[rt * 128 + ((n + 0 + rt) & 127)] = v.x;
      rows[rt * 128 + ((n + 1 + rt) & 127)] = v.y;
      rows[rt * 128 + ((n + 2 + rt) & 127)] = v.z;
      rows[rt * 128 + ((n + 3 + rt) & 127)] = v.w;
    }
    __syncthreads();
    {
      float* op = out + (size_t)b * NDIM * TLEN + (size_t)h * 128 * TLEN + t0 + lane;
#pragma unroll 8
      for (int i = 0; i < 32; ++i) {
        int n = w * 32 + i;
        op[(size_t)n * TLEN] = rows[lane * 128 + ((n + lane) & 127)];
      }
    }
    __syncthreads();
  }
}

// Rescore part: block = (token-group of 8) x (c4 chunk of 256 codes).
// Thread = one code: SEQUENTIAL fp32 fmaf chain over k ascending, then
// eu = 2.0f - 2.0f*acc — bit-identical per (code, token) to the validated
// np-replicating chain (R3/R13/R14). Per-token winner merged via u64
// atomicMin on (ordered(eu)<<32 | code): exact min-value-then-min-index,
// order-independent -> deterministic.
__global__
__attribute__((amdgpu_flat_work_group_size(256, 256)))
void svq_rescore_part(const float* __restrict__ x,
                      const float* __restrict__ embT,
                      const unsigned int* __restrict__ ctr,
                      const int* __restrict__ list,
                      unsigned long long* __restrict__ tokmin,
                      int cap) {
  __shared__ float xs[8][256];
  __shared__ int   toks[8];
  const int tid  = threadIdx.x;
  const int lane = tid & 63;
  int n = (int)*ctr;
  if (n > cap) n = cap;
  const int ngroups = ((n + 7) >> 3) << 2;
  for (int g = blockIdx.x; g < ngroups; g += gridDim.x) {
    const int tg = g >> 2, c4 = g & 3;
    const int base = tg << 3;
    const int m = (n - base) < 8 ? (n - base) : 8;   // >=1
    if (tid < 8) toks[tid] = list[base + (tid < m ? tid : (m - 1))];
    __syncthreads();
#pragma unroll
    for (int tt = 0; tt < 8; ++tt) {
      int tok = toks[tt];
      xs[tt][tid] = x[(size_t)(tok >> 12) * NDIM * TLEN + (size_t)tid * TLEN + (tok & (TLEN - 1))];
    }
    __syncthreads();

    float a[8];
#pragma unroll
    for (int tt = 0; tt < 8; ++tt) a[tt] = 0.0f;

    const float* et = embT + (size_t)(c4 * 256 + tid);
#pragma unroll 2
    for (int k = 0; k < NDIM; k += 4) {
      float4 xv[8];
#pragma unroll
      for (int tt = 0; tt < 8; ++tt) xv[tt] = *(const float4*)&xs[tt][k];
      float ev0 = et[(size_t)(k + 0) * NCODE];
      float ev1 = et[(size_t)(k + 1) * NCODE];
      float ev2 = et[(size_t)(k + 2) * NCODE];
      float ev3 = et[(size_t)(k + 3) * NCODE];
#pragma unroll
      for (int tt = 0; tt < 8; ++tt) a[tt] = fmaf(xv[tt].x, ev0, a[tt]);
#pragma unroll
      for (int tt = 0; tt < 8; ++tt) a[tt] = fmaf(xv[tt].y, ev1, a[tt]);
#pragma unroll
      for (int tt = 0; tt < 8; ++tt) a[tt] = fmaf(xv[tt].z, ev2, a[tt]);
#pragma unroll
      for (int tt = 0; tt < 8; ++tt) a[tt] = fmaf(xv[tt].w, ev3, a[tt]);
    }

    // per token: wave-reduce (min eu, lowest code) over this chunk's 256 codes
#pragma unroll
    for (int tt = 0; tt < 8; ++tt) {
      float v = 2.0f - 2.0f * a[tt];
      int   ix = c4 * 256 + tid;
#pragma unroll
      for (int off = 32; off >= 1; off >>= 1) {
        float ov = __shfl_xor(v, off);
        int   oi = __shfl_xor(ix, off);
        if (ov < v || (ov == v && oi < ix)) { v = ov; ix = oi; }
      }
      if (lane == 0 && tt < m) {
        unsigned long long key = ((unsigned long long)ordf(v) << 32) | (unsigned int)ix;
        atomicMin(&tokmin[base + tt], key);
      }
    }
    __syncthreads();   // before next iteration overwrites xs/toks
  }
}

// Rescore write: one block per flagged token (grid-stride); gather winner row.
__global__ __launch_bounds__(256) void svq_rescore_write(const float* __restrict__ emb,
                                                         float* __restrict__ out,
                                                         const unsigned int* __restrict__ ctr,
                                                         const int* __restrict__ list,
                                                         const unsigned long long* __restrict__ tokmin,
                                                         int cap) {
  const int tid = threadIdx.x;
  int n = (int)*ctr;
  if (n > cap) n = cap;
  for (int i = blockIdx.x; i < n; i += gridDim.x) {
    unsigned long long key = tokmin[i];
    if (key == ~0ull) continue;
    const int code = (int)(unsigned int)(key & 0xFFFFFFFFull);
    const int tok = list[i];
    out[(size_t)(tok >> 12) * NDIM * TLEN + (size_t)tid * TLEN + (tok & (TLEN - 1))] =
        emb[(size_t)code * NDIM + tid];
  }
}

extern "C" void kernel_launch(void* const* d_in, const int* in_sizes, int n_in,
                              void* d_out, int out_size, void* d_ws, size_t ws_size,
                              hipStream_t stream) {
  (void)in_sizes; (void)n_in; (void)out_size;
  const float* x   = (const float*)d_in[0];
  const float* emb = (const float*)d_in[1];
  float* out = (float*)d_out;

  // ws layout: ehi 512KB | embT 1MB | ctr 16B | tokmin cap*8 | list cap*4
  unsigned short*     ehi    = (unsigned short*)d_ws;
  float*              embT   = (float*)((char*)d_ws + (size_t)512 * 1024);
  unsigned int*       ctr    = (unsigned int*)((char*)d_ws + (size_t)1536 * 1024);
  long avail = (long)ws_size - (long)1536 * 1024 - 16;
  int cap = avail > 0 ? (int)(avail / 12 < 32768 ? avail / 12 : 32768) : 0;
  unsigned long long* tokmin = (unsigned long long*)((char*)ctr + 16);
  int*                lst    = (int*)((char*)tokmin + (size_t)cap * 8);

  svq_prep_emb<<<dim3(1024), dim3(256), 0, stream>>>(emb, ehi, ctr, tokmin, cap);
  svq_transpose<<<dim3(64), dim3(256), 0, stream>>>(emb, embT);
  svq_main<<<dim3(NBATCH * (TLEN / BT)), dim3(256), 0, stream>>>(
      x, emb, (const short8*)ehi, out, ctr, lst, cap);
  svq_rescore_part<<<dim3(2048), dim3(256), 0, stream>>>(x, embT, ctr, lst, tokmin, cap);
  svq_rescore_write<<<dim3(2048), dim3(256), 0, stream>>>(emb, out, ctr, lst, tokmin, cap);
}

// Round 16
// 150.948 us; speedup vs baseline: 2.1786x; 1.0626x over previous
//
#include <hip/hip_runtime.h>
#include <math.h>

typedef __attribute__((ext_vector_type(8))) short short8;   // 8 bf16 in 4 VGPRs
typedef __attribute__((ext_vector_type(4))) float f32x4;

#define NCODE  1024
#define NDIM   256
#define TLEN   4096
#define NBATCH 16
#define BT     64
#define TAU    2.5e-2f

__device__ __forceinline__ unsigned short f2bf(float f) {
  unsigned int u = __float_as_uint(f);
  u += 0x7FFFu + ((u >> 16) & 1u);          // round-to-nearest-even
  return (unsigned short)(u >> 16);
}

// Ordered-monotone encoding of float for u64 atomicMin (min eu, then min idx).
__device__ __forceinline__ unsigned int ordf(float f) {
  unsigned int u = __float_as_uint(f);
  return (u & 0x80000000u) ? ~u : (u | 0x80000000u);
}

// Codebook -> bf16 MFMA A-fragment order; reset tie counter; init tokmin.
__global__ __launch_bounds__(256) void svq_prep_emb(const float* __restrict__ emb,
                                                    unsigned short* __restrict__ ehi,
                                                    unsigned int* __restrict__ ctr,
                                                    unsigned long long* __restrict__ tokmin,
                                                    int cap) {
  int gtid = blockIdx.x * 256 + threadIdx.x;
  if (gtid == 0) *ctr = 0u;
  if (gtid < cap) tokmin[gtid] = ~0ull;
  int tid  = gtid;                              // 0 .. 262143
  int j    = tid & 7;
  int lane = (tid >> 3) & 63;
  int blk  = tid >> 9;                          // ct*8 + ks
  int ct   = blk >> 3, ks = blk & 7;
  int row  = (ct << 4) | (lane & 15);
  int k    = (ks << 5) | ((lane >> 4) << 3) | j;
  ehi[tid] = f2bf(emb[row * NDIM + k]);
}

// Bit-exact tiled transpose emb[1024][256] -> embT[256][1024].
__global__ __launch_bounds__(256) void svq_transpose(const float* __restrict__ emb,
                                                     float* __restrict__ embT) {
  __shared__ float tile[64][65];
  const int bc = blockIdx.x >> 2;        // code tile 0..15
  const int bd = blockIdx.x & 3;         // dim tile 0..3
  const int r0 = bc * 64, c0 = bd * 64;
  const int lc = threadIdx.x & 63;
  const int lr = threadIdx.x >> 6;       // 0..3
#pragma unroll
  for (int i = 0; i < 16; ++i) {
    int r = lr * 16 + i;
    tile[r][lc] = emb[(size_t)(r0 + r) * NDIM + c0 + lc];
  }
  __syncthreads();
#pragma unroll
  for (int i = 0; i < 16; ++i) {
    int c = lr * 16 + i;
    embT[(size_t)(c0 + c) * NCODE + r0 + lc] = tile[lc][c];
  }
}

// ===== svq_main: byte-for-byte the R9/R13/R14/R15 version (PASSED 4x) =====

#define MFMA_AGPR(ACC, A, B)                                                    \
  asm("v_mfma_f32_16x16x32_bf16 %0, %1, %2, %0" : "+a"(ACC) : "v"(A), "v"(B))

#define KSTEP(KS)                                                               \
  {                                                                             \
    const int kb0 = ((KS) * 32 + khalf) * 2;                                    \
    _Pragma("unroll")                                                           \
    for (int ti = 0; ti < 4; ++ti) {                                            \
      const int off = bbase + (kb0 ^ bswz) + ti * 8192;                         \
      short8 bh = *(const short8*)(xhi_s + off);                                \
      _Pragma("unroll")                                                         \
      for (int ci = 0; ci < 4; ++ci)                                            \
        MFMA_AGPR(acc[ci][ti], ah[ci], bh);                                     \
    }                                                                           \
    if ((KS) < 7) {                                                             \
      _Pragma("unroll")                                                         \
      for (int ci = 0; ci < 4; ++ci)                                            \
        ah[ci] = pe_h[(ci * 8 + (KS) + 1) * 64];                                \
    }                                                                           \
  }

__global__
__attribute__((amdgpu_flat_work_group_size(256, 256)))
__attribute__((amdgpu_waves_per_eu(4, 4)))
void svq_main(const float* __restrict__ x,
              const float* __restrict__ emb,
              const short8* __restrict__ ehi,
              float* __restrict__ out,
              unsigned int* __restrict__ ctr,
              int* __restrict__ list,
              int cap) {
  __shared__ char smem[32768];   // x_hi [64 t][512 B]; reused by reduce+epilogue
  const int tid  = threadIdx.x;
  const int lane = tid & 63;
  const int w    = tid >> 6;                 // wave id 0..3
  const int bx   = blockIdx.x;
  const int b    = bx >> 6;                  // batch
  const int t0   = (bx & 63) * BT;           // token-tile start

  {
    const float* xb = x + (size_t)b * NDIM * TLEN + t0;
    const int tl = lane;
    const int sw = (tl & 7) << 4;
#pragma unroll 4
    for (int it = 0; it < 16; ++it) {
      const int kb = w * 4 + it * 16;
      float v0 = xb[(size_t)(kb + 0) * TLEN + tl];
      float v1 = xb[(size_t)(kb + 1) * TLEN + tl];
      float v2 = xb[(size_t)(kb + 2) * TLEN + tl];
      float v3 = xb[(size_t)(kb + 3) * TLEN + tl];
      unsigned short h0 = f2bf(v0), h1 = f2bf(v1), h2 = f2bf(v2), h3 = f2bf(v3);
      unsigned long long ph = (unsigned long long)h0 | ((unsigned long long)h1 << 16)
                            | ((unsigned long long)h2 << 32) | ((unsigned long long)h3 << 48);
      *(unsigned long long*)(smem + tl * 512 + ((kb * 2) ^ sw)) = ph;
    }
  }
  __syncthreads();

  float bestv[4], secv[4];
  int   besti[4];
#pragma unroll
  for (int ti = 0; ti < 4; ++ti) {
    bestv[ti] = __builtin_inff(); secv[ti] = __builtin_inff(); besti[ti] = 0;
  }

  const char* xhi_s = smem;
  const int bbase = (lane & 15) * 512;
  const int bswz  = (lane & 7) << 4;
  const int khalf = (lane >> 4) << 3;

  for (int cc = 0; cc < 4; ++cc) {
    const int ctb = w * 16 + cc * 4;
    const short8* pe_h = ehi + (size_t)ctb * 8 * 64 + lane;

    f32x4 acc[4][4];
#pragma unroll
    for (int ci = 0; ci < 4; ++ci)
#pragma unroll
      for (int ti = 0; ti < 4; ++ti)
        acc[ci][ti] = (f32x4){0.f, 0.f, 0.f, 0.f};

    short8 ah[4];
#pragma unroll
    for (int ci = 0; ci < 4; ++ci) ah[ci] = pe_h[ci * 8 * 64];

    asm volatile("s_nop 1");

    KSTEP(0) KSTEP(1) KSTEP(2) KSTEP(3)
    KSTEP(4) KSTEP(5) KSTEP(6) KSTEP(7)

    asm volatile("s_nop 7\n\ts_nop 7\n\ts_nop 7");

#pragma unroll
    for (int ci = 0; ci < 4; ++ci) {
      const int cbase = (ctb + ci) * 16 + ((lane >> 4) << 2);
#pragma unroll
      for (int j = 0; j < 4; ++j) {
#pragma unroll
        for (int ti = 0; ti < 4; ++ti) {
          float eu = fmaf(-2.0f, acc[ci][ti][j], 2.0f);
          if (eu < bestv[ti])      { secv[ti] = bestv[ti]; bestv[ti] = eu; besti[ti] = cbase + j; }
          else if (eu < secv[ti])  { secv[ti] = eu; }
        }
      }
    }
  }

  __syncthreads();

  float* red_v = (float*)smem;
  float* red_s = (float*)(smem + 1024);
  int*   red_i = (int*)(smem + 2048);
  int*   idxf  = (int*)(smem + 3072);

#pragma unroll
  for (int ti = 0; ti < 4; ++ti) {
    float v = bestv[ti], s = secv[ti]; int ix = besti[ti];
#pragma unroll
    for (int off = 16; off < 64; off <<= 1) {
      float ov = __shfl_xor(v, off);
      float os = __shfl_xor(s, off);
      int   oi = __shfl_xor(ix, off);
      if (ov < v || (ov == v && oi < ix)) { s = fminf(v, os); v = ov; ix = oi; }
      else                                { s = fminf(s, ov); }
    }
    if (lane < 16) {
      red_v[w * 64 + ti * 16 + lane] = v;
      red_s[w * 64 + ti * 16 + lane] = s;
      red_i[w * 64 + ti * 16 + lane] = ix;
    }
  }
  __syncthreads();
  if (tid < 64) {
    float v = red_v[tid], s = red_s[tid]; int ix = red_i[tid];
#pragma unroll
    for (int ww = 1; ww < 4; ++ww) {
      float ov = red_v[ww * 64 + tid], os = red_s[ww * 64 + tid];
      int   oi = red_i[ww * 64 + tid];
      if (ov < v || (ov == v && oi < ix)) { s = fminf(v, os); v = ov; ix = oi; }
      else                                { s = fminf(s, ov); }
    }
    idxf[tid] = ix;
    if (s - v < TAU) {
      unsigned int slot = atomicAdd(ctr, 1u);
      if ((int)slot < cap) list[slot] = (b << 12) | (t0 + tid);
    }
  }
  __syncthreads();

  const int rt = tid >> 2, q = tid & 3;
  const int code = idxf[rt];
  __syncthreads();

  float* rows = (float*)smem;
  const float4* src = (const float4*)(emb + (size_t)code * NDIM);
  for (int h = 0; h < 2; ++h) {
#pragma unroll
    for (int i = 0; i < 8; ++i) {
      float4 v = src[h * 32 + q + 4 * i];
      int n = 4 * (q + 4 * i);
      rows[rt * 128 + ((n + 0 + rt) & 127)] = v.x;
      rows[rt * 128 + ((n + 1 + rt) & 127)] = v.y;
      rows[rt * 128 + ((n + 2 + rt) & 127)] = v.z;
      rows[rt * 128 + ((n + 3 + rt) & 127)] = v.w;
    }
    __syncthreads();
    {
      float* op = out + (size_t)b * NDIM * TLEN + (size_t)h * 128 * TLEN + t0 + lane;
#pragma unroll 8
      for (int i = 0; i < 32; ++i) {
        int n = w * 32 + i;
        op[(size_t)n * TLEN] = rows[lane * 128 + ((n + lane) & 127)];
      }
    }
    __syncthreads();
  }
}

// Gather flagged tokens' x columns into compact xcomp[i][256] — the strided
// (16 KB-stride) column read happens ONCE here instead of 4x in the part
// kernel (R15: 109 MB HBM re-fetch). Bit-exact copy.
__global__ __launch_bounds__(256) void svq_gather_x(const float* __restrict__ x,
                                                    const unsigned int* __restrict__ ctr,
                                                    const int* __restrict__ list,
                                                    float* __restrict__ xcomp,
                                                    int cap) {
  const int tid = threadIdx.x;
  int n = (int)*ctr;
  if (n > cap) n = cap;
  for (int i = blockIdx.x; i < n; i += gridDim.x) {
    const int tok = list[i];
    xcomp[(size_t)i * NDIM + tid] =
        x[(size_t)(tok >> 12) * NDIM * TLEN + (size_t)tid * TLEN + (tok & (TLEN - 1))];
  }
}

// Rescore part: block = (token-group of 8) x (c4 chunk of 256 codes).
// Thread = one code: SEQUENTIAL fp32 fmaf chain over k ascending, then
// eu = 2.0f - 2.0f*acc — bit-identical per (code, token) to the validated
// np-replicating chain (R3/R13/R14/R15). Winner merged via u64 atomicMin on
// (ordered(eu)<<32 | code): exact min-value-then-min-index, deterministic.
__global__
__attribute__((amdgpu_flat_work_group_size(256, 256)))
void svq_rescore_part(const float* __restrict__ xcomp,
                      const float* __restrict__ embT,
                      const unsigned int* __restrict__ ctr,
                      unsigned long long* __restrict__ tokmin,
                      int cap) {
  __shared__ float xs[8][256];
  const int tid  = threadIdx.x;
  const int lane = tid & 63;
  int n = (int)*ctr;
  if (n > cap) n = cap;
  const int ngroups = ((n + 7) >> 3) << 2;
  for (int g = blockIdx.x; g < ngroups; g += gridDim.x) {
    const int tg = g >> 2, c4 = g & 3;
    const int base = tg << 3;
    const int m = (n - base) < 8 ? (n - base) : 8;   // >=1
#pragma unroll
    for (int tt = 0; tt < 8; ++tt) {
      int sl = tt < m ? tt : (m - 1);        // duplicate last token in dead slots
      xs[tt][tid] = xcomp[(size_t)(base + sl) * NDIM + tid];
    }
    __syncthreads();

    float a[8];
#pragma unroll
    for (int tt = 0; tt < 8; ++tt) a[tt] = 0.0f;

    const float* et = embT + (size_t)(c4 * 256 + tid);
#pragma unroll 2
    for (int k = 0; k < NDIM; k += 4) {
      float4 xv[8];
#pragma unroll
      for (int tt = 0; tt < 8; ++tt) xv[tt] = *(const float4*)&xs[tt][k];
      float ev0 = et[(size_t)(k + 0) * NCODE];
      float ev1 = et[(size_t)(k + 1) * NCODE];
      float ev2 = et[(size_t)(k + 2) * NCODE];
      float ev3 = et[(size_t)(k + 3) * NCODE];
#pragma unroll
      for (int tt = 0; tt < 8; ++tt) a[tt] = fmaf(xv[tt].x, ev0, a[tt]);
#pragma unroll
      for (int tt = 0; tt < 8; ++tt) a[tt] = fmaf(xv[tt].y, ev1, a[tt]);
#pragma unroll
      for (int tt = 0; tt < 8; ++tt) a[tt] = fmaf(xv[tt].z, ev2, a[tt]);
#pragma unroll
      for (int tt = 0; tt < 8; ++tt) a[tt] = fmaf(xv[tt].w, ev3, a[tt]);
    }

    // per token: wave-reduce (min eu, lowest code) over this chunk's 256 codes
#pragma unroll
    for (int tt = 0; tt < 8; ++tt) {
      float v = 2.0f - 2.0f * a[tt];
      int   ix = c4 * 256 + tid;
#pragma unroll
      for (int off = 32; off >= 1; off >>= 1) {
        float ov = __shfl_xor(v, off);
        int   oi = __shfl_xor(ix, off);
        if (ov < v || (ov == v && oi < ix)) { v = ov; ix = oi; }
      }
      if (lane == 0 && tt < m) {
        unsigned long long key = ((unsigned long long)ordf(v) << 32) | (unsigned int)ix;
        atomicMin(&tokmin[base + tt], key);
      }
    }
    __syncthreads();   // before next iteration overwrites xs
  }
}

// Rescore write: one block per flagged token (grid-stride); gather winner row.
__global__ __launch_bounds__(256) void svq_rescore_write(const float* __restrict__ emb,
                                                         float* __restrict__ out,
                                                         const unsigned int* __restrict__ ctr,
                                                         const int* __restrict__ list,
                                                         const unsigned long long* __restrict__ tokmin,
                                                         int cap) {
  const int tid = threadIdx.x;
  int n = (int)*ctr;
  if (n > cap) n = cap;
  for (int i = blockIdx.x; i < n; i += gridDim.x) {
    unsigned long long key = tokmin[i];
    if (key == ~0ull) continue;
    const int code = (int)(unsigned int)(key & 0xFFFFFFFFull);
    const int tok = list[i];
    out[(size_t)(tok >> 12) * NDIM * TLEN + (size_t)tid * TLEN + (tok & (TLEN - 1))] =
        emb[(size_t)code * NDIM + tid];
  }
}

extern "C" void kernel_launch(void* const* d_in, const int* in_sizes, int n_in,
                              void* d_out, int out_size, void* d_ws, size_t ws_size,
                              hipStream_t stream) {
  (void)in_sizes; (void)n_in; (void)out_size;
  const float* x   = (const float*)d_in[0];
  const float* emb = (const float*)d_in[1];
  float* out = (float*)d_out;

  // ws layout: ehi 512KB | embT 1MB | ctr 16B | tokmin cap*8 | list cap*4 | xcomp cap*1024
  unsigned short*     ehi    = (unsigned short*)d_ws;
  float*              embT   = (float*)((char*)d_ws + (size_t)512 * 1024);
  unsigned int*       ctr    = (unsigned int*)((char*)d_ws + (size_t)1536 * 1024);
  long avail = (long)ws_size - (long)1536 * 1024 - 16;
  int cap = avail > 0 ? (int)(avail / 1040 < 32768 ? avail / 1040 : 32768) : 0;
  unsigned long long* tokmin = (unsigned long long*)((char*)ctr + 16);
  int*                lst    = (int*)((char*)tokmin + (size_t)cap * 8);
  float*              xcomp  = (float*)((char*)lst + (size_t)cap * 4);

  svq_prep_emb<<<dim3(1024), dim3(256), 0, stream>>>(emb, ehi, ctr, tokmin, cap);
  svq_transpose<<<dim3(64), dim3(256), 0, stream>>>(emb, embT);
  svq_main<<<dim3(NBATCH * (TLEN / BT)), dim3(256), 0, stream>>>(
      x, emb, (const short8*)ehi, out, ctr, lst, cap);
  svq_gather_x<<<dim3(2048), dim3(256), 0, stream>>>(x, ctr, lst, xcomp, cap);
  svq_rescore_part<<<dim3(2048), dim3(256), 0, stream>>>(xcomp, embT, ctr, tokmin, cap);
  svq_rescore_write<<<dim3(2048), dim3(256), 0, stream>>>(emb, out, ctr, lst, tokmin, cap);
}

// Round 18
// 143.604 us; speedup vs baseline: 2.2900x; 1.0511x over previous
//
#include <hip/hip_runtime.h>
#include <math.h>

typedef __attribute__((ext_vector_type(8))) short short8;   // 8 bf16 in 4 VGPRs
typedef __attribute__((ext_vector_type(4))) float f32x4;

#define NCODE  1024
#define NDIM   256
#define TLEN   4096
#define NBATCH 16
#define BT     64
#define TAU    2.5e-2f

__device__ __forceinline__ unsigned short f2bf(float f) {
  unsigned int u = __float_as_uint(f);
  u += 0x7FFFu + ((u >> 16) & 1u);          // round-to-nearest-even
  return (unsigned short)(u >> 16);
}

// Ordered-monotone encoding of float for u64 atomicMin (min eu, then min idx).
__device__ __forceinline__ unsigned int ordf(float f) {
  unsigned int u = __float_as_uint(f);
  return (u & 0x80000000u) ? ~u : (u | 0x80000000u);
}

// Codebook -> bf16 MFMA A-fragment order; reset tie counter; init tokmin.
__global__ __launch_bounds__(256) void svq_prep_emb(const float* __restrict__ emb,
                                                    unsigned short* __restrict__ ehi,
                                                    unsigned int* __restrict__ ctr,
                                                    unsigned long long* __restrict__ tokmin,
                                                    int cap) {
  int gtid = blockIdx.x * 256 + threadIdx.x;
  if (gtid == 0) *ctr = 0u;
  if (gtid < cap) tokmin[gtid] = ~0ull;
  int tid  = gtid;                              // 0 .. 262143
  int j    = tid & 7;
  int lane = (tid >> 3) & 63;
  int blk  = tid >> 9;                          // ct*8 + ks
  int ct   = blk >> 3, ks = blk & 7;
  int row  = (ct << 4) | (lane & 15);
  int k    = (ks << 5) | ((lane >> 4) << 3) | j;
  ehi[tid] = f2bf(emb[row * NDIM + k]);
}

// Bit-exact tiled transpose emb[1024][256] -> embT[256][1024].
__global__ __launch_bounds__(256) void svq_transpose(const float* __restrict__ emb,
                                                     float* __restrict__ embT) {
  __shared__ float tile[64][65];
  const int bc = blockIdx.x >> 2;        // code tile 0..15
  const int bd = blockIdx.x & 3;         // dim tile 0..3
  const int r0 = bc * 64, c0 = bd * 64;
  const int lc = threadIdx.x & 63;
  const int lr = threadIdx.x >> 6;       // 0..3
#pragma unroll
  for (int i = 0; i < 16; ++i) {
    int r = lr * 16 + i;
    tile[r][lc] = emb[(size_t)(r0 + r) * NDIM + c0 + lc];
  }
  __syncthreads();
#pragma unroll
  for (int i = 0; i < 16; ++i) {
    int c = lr * 16 + i;
    embT[(size_t)(c0 + c) * NCODE + r0 + lc] = tile[lc][c];
  }
}

// ===== svq_main: R9/R13-R16 core (PASSED 5x) + inline flagged-x gather =====

#define MFMA_AGPR(ACC, A, B)                                                    \
  asm("v_mfma_f32_16x16x32_bf16 %0, %1, %2, %0" : "+a"(ACC) : "v"(A), "v"(B))

#define KSTEP(KS)                                                               \
  {                                                                             \
    const int kb0 = ((KS) * 32 + khalf) * 2;                                    \
    _Pragma("unroll")                                                           \
    for (int ti = 0; ti < 4; ++ti) {                                            \
      const int off = bbase + (kb0 ^ bswz) + ti * 8192;                         \
      short8 bh = *(const short8*)(xhi_s + off);                                \
      _Pragma("unroll")                                                         \
      for (int ci = 0; ci < 4; ++ci)                                            \
        MFMA_AGPR(acc[ci][ti], ah[ci], bh);                                     \
    }                                                                           \
    if ((KS) < 7) {                                                             \
      _Pragma("unroll")                                                         \
      for (int ci = 0; ci < 4; ++ci)                                            \
        ah[ci] = pe_h[(ci * 8 + (KS) + 1) * 64];                                \
    }                                                                           \
  }

__global__
__attribute__((amdgpu_flat_work_group_size(256, 256)))
__attribute__((amdgpu_waves_per_eu(4, 4)))
void svq_main(const float* __restrict__ x,
              const float* __restrict__ emb,
              const short8* __restrict__ ehi,
              float* __restrict__ out,
              unsigned int* __restrict__ ctr,
              int* __restrict__ list,
              float* __restrict__ xcomp,
              int cap) {
  __shared__ char smem[32768];   // x_hi [64 t][512 B]; reused by reduce+epilogue
  const int tid  = threadIdx.x;
  const int lane = tid & 63;
  const int w    = tid >> 6;                 // wave id 0..3
  const int bx   = blockIdx.x;
  const int b    = bx >> 6;                  // batch
  const int t0   = (bx & 63) * BT;           // token-tile start

  {
    const float* xb = x + (size_t)b * NDIM * TLEN + t0;
    const int tl = lane;
    const int sw = (tl & 7) << 4;
#pragma unroll 4
    for (int it = 0; it < 16; ++it) {
      const int kb = w * 4 + it * 16;
      float v0 = xb[(size_t)(kb + 0) * TLEN + tl];
      float v1 = xb[(size_t)(kb + 1) * TLEN + tl];
      float v2 = xb[(size_t)(kb + 2) * TLEN + tl];
      float v3 = xb[(size_t)(kb + 3) * TLEN + tl];
      unsigned short h0 = f2bf(v0), h1 = f2bf(v1), h2 = f2bf(v2), h3 = f2bf(v3);
      unsigned long long ph = (unsigned long long)h0 | ((unsigned long long)h1 << 16)
                            | ((unsigned long long)h2 << 32) | ((unsigned long long)h3 << 48);
      *(unsigned long long*)(smem + tl * 512 + ((kb * 2) ^ sw)) = ph;
    }
  }
  __syncthreads();

  float bestv[4], secv[4];
  int   besti[4];
#pragma unroll
  for (int ti = 0; ti < 4; ++ti) {
    bestv[ti] = __builtin_inff(); secv[ti] = __builtin_inff(); besti[ti] = 0;
  }

  const char* xhi_s = smem;
  const int bbase = (lane & 15) * 512;
  const int bswz  = (lane & 7) << 4;
  const int khalf = (lane >> 4) << 3;

  for (int cc = 0; cc < 4; ++cc) {
    const int ctb = w * 16 + cc * 4;
    const short8* pe_h = ehi + (size_t)ctb * 8 * 64 + lane;

    f32x4 acc[4][4];
#pragma unroll
    for (int ci = 0; ci < 4; ++ci)
#pragma unroll
      for (int ti = 0; ti < 4; ++ti)
        acc[ci][ti] = (f32x4){0.f, 0.f, 0.f, 0.f};

    short8 ah[4];
#pragma unroll
    for (int ci = 0; ci < 4; ++ci) ah[ci] = pe_h[ci * 8 * 64];

    asm volatile("s_nop 1");

    KSTEP(0) KSTEP(1) KSTEP(2) KSTEP(3)
    KSTEP(4) KSTEP(5) KSTEP(6) KSTEP(7)

    asm volatile("s_nop 7\n\ts_nop 7\n\ts_nop 7");

#pragma unroll
    for (int ci = 0; ci < 4; ++ci) {
      const int cbase = (ctb + ci) * 16 + ((lane >> 4) << 2);
#pragma unroll
      for (int j = 0; j < 4; ++j) {
#pragma unroll
        for (int ti = 0; ti < 4; ++ti) {
          float eu = fmaf(-2.0f, acc[ci][ti][j], 2.0f);
          if (eu < bestv[ti])      { secv[ti] = bestv[ti]; bestv[ti] = eu; besti[ti] = cbase + j; }
          else if (eu < secv[ti])  { secv[ti] = eu; }
        }
      }
    }
  }

  __syncthreads();

  float* red_v = (float*)smem;
  float* red_s = (float*)(smem + 1024);
  int*   red_i = (int*)(smem + 2048);
  int*   idxf  = (int*)(smem + 3072);
  int*   flag_slot = (int*)(smem + 3328);

#pragma unroll
  for (int ti = 0; ti < 4; ++ti) {
    float v = bestv[ti], s = secv[ti]; int ix = besti[ti];
#pragma unroll
    for (int off = 16; off < 64; off <<= 1) {
      float ov = __shfl_xor(v, off);
      float os = __shfl_xor(s, off);
      int   oi = __shfl_xor(ix, off);
      if (ov < v || (ov == v && oi < ix)) { s = fminf(v, os); v = ov; ix = oi; }
      else                                { s = fminf(s, ov); }
    }
    if (lane < 16) {
      red_v[w * 64 + ti * 16 + lane] = v;
      red_s[w * 64 + ti * 16 + lane] = s;
      red_i[w * 64 + ti * 16 + lane] = ix;
    }
  }
  __syncthreads();
  if (tid < 64) {
    float v = red_v[tid], s = red_s[tid]; int ix = red_i[tid];
#pragma unroll
    for (int ww = 1; ww < 4; ++ww) {
      float ov = red_v[ww * 64 + tid], os = red_s[ww * 64 + tid];
      int   oi = red_i[ww * 64 + tid];
      if (ov < v || (ov == v && oi < ix)) { s = fminf(v, os); v = ov; ix = oi; }
      else                                { s = fminf(s, ov); }
    }
    idxf[tid] = ix;
    int fs = -1;
    if (s - v < TAU) {
      unsigned int slot = atomicAdd(ctr, 1u);
      if ((int)slot < cap) { list[slot] = (b << 12) | (t0 + tid); fs = (int)slot; }
    }
    flag_slot[tid] = fs;
  }
  __syncthreads();

  // inline gather: copy each flagged token's exact fp32 x column into xcomp
  for (int tt = 0; tt < 64; ++tt) {
    int fs = flag_slot[tt];
    if (fs >= 0)
      xcomp[(size_t)fs * NDIM + tid] =
          x[(size_t)b * NDIM * TLEN + (size_t)tid * TLEN + t0 + tt];
  }

  const int rt = tid >> 2, q = tid & 3;
  const int code = idxf[rt];
  __syncthreads();

  float* rows = (float*)smem;
  const float4* src = (const float4*)(emb + (size_t)code * NDIM);
  for (int h = 0; h < 2; ++h) {
#pragma unroll
    for (int i = 0; i < 8; ++i) {
      float4 v = src[h * 32 + q + 4 * i];
      int n = 4 * (q + 4 * i);
      rows[rt * 128 + ((n + 0 + rt) & 127)] = v.x;
      rows[rt * 128 + ((n + 1 + rt) & 127)] = v.y;
      rows[rt * 128 + ((n + 2 + rt) & 127)] = v.z;
      rows[rt * 128 + ((n + 3 + rt) & 127)] = v.w;
    }
    __syncthreads();
    {
      float* op = out + (size_t)b * NDIM * TLEN + (size_t)h * 128 * TLEN + t0 + lane;
#pragma unroll 8
      for (int i = 0; i < 32; ++i) {
        int n = w * 32 + i;
        op[(size_t)n * TLEN] = rows[lane * 128 + ((n + lane) & 127)];
      }
    }
    __syncthreads();
  }
}

// Rescore part (R16-validated version): block = (token-group of 8) x (c4
// chunk of 256 codes). Thread = one code: SEQUENTIAL fp32 fmaf chain over k
// ascending, then eu = 2.0f - 2.0f*acc — bit-identical per (code, token) to
// the validated np-replicating chain. Winner merged via u64 atomicMin on
// (ordered(eu)<<32 | code): exact min-value-then-min-index, deterministic.
__global__
__attribute__((amdgpu_flat_work_group_size(256, 256)))
void svq_rescore_part(const float* __restrict__ xcomp,
                      const float* __restrict__ embT,
                      const unsigned int* __restrict__ ctr,
                      unsigned long long* __restrict__ tokmin,
                      int cap) {
  __shared__ float xs[8][256];
  const int tid  = threadIdx.x;
  const int lane = tid & 63;
  int n = (int)*ctr;
  if (n > cap) n = cap;
  const int ngroups = ((n + 7) >> 3) << 2;
  for (int g = blockIdx.x; g < ngroups; g += gridDim.x) {
    const int tg = g >> 2, c4 = g & 3;
    const int base = tg << 3;
    const int m = (n - base) < 8 ? (n - base) : 8;   // >=1
#pragma unroll
    for (int tt = 0; tt < 8; ++tt) {
      int sl = tt < m ? tt : (m - 1);        // duplicate last token in dead slots
      xs[tt][tid] = xcomp[(size_t)(base + sl) * NDIM + tid];
    }
    __syncthreads();

    float a[8];
#pragma unroll
    for (int tt = 0; tt < 8; ++tt) a[tt] = 0.0f;

    const float* et = embT + (size_t)(c4 * 256 + tid);
#pragma unroll 2
    for (int k = 0; k < NDIM; k += 4) {
      float4 xv[8];
#pragma unroll
      for (int tt = 0; tt < 8; ++tt) xv[tt] = *(const float4*)&xs[tt][k];
      float ev0 = et[(size_t)(k + 0) * NCODE];
      float ev1 = et[(size_t)(k + 1) * NCODE];
      float ev2 = et[(size_t)(k + 2) * NCODE];
      float ev3 = et[(size_t)(k + 3) * NCODE];
#pragma unroll
      for (int tt = 0; tt < 8; ++tt) a[tt] = fmaf(xv[tt].x, ev0, a[tt]);
#pragma unroll
      for (int tt = 0; tt < 8; ++tt) a[tt] = fmaf(xv[tt].y, ev1, a[tt]);
#pragma unroll
      for (int tt = 0; tt < 8; ++tt) a[tt] = fmaf(xv[tt].z, ev2, a[tt]);
#pragma unroll
      for (int tt = 0; tt < 8; ++tt) a[tt] = fmaf(xv[tt].w, ev3, a[tt]);
    }

    // per token: wave-reduce (min eu, lowest code) over this chunk's 256 codes
#pragma unroll
    for (int tt = 0; tt < 8; ++tt) {
      float v = 2.0f - 2.0f * a[tt];
      int   ix = c4 * 256 + tid;
#pragma unroll
      for (int off = 32; off >= 1; off >>= 1) {
        float ov = __shfl_xor(v, off);
        int   oi = __shfl_xor(ix, off);
        if (ov < v || (ov == v && oi < ix)) { v = ov; ix = oi; }
      }
      if (lane == 0 && tt < m) {
        unsigned long long key = ((unsigned long long)ordf(v) << 32) | (unsigned int)ix;
        atomicMin(&tokmin[base + tt], key);
      }
    }
    __syncthreads();   // before next iteration overwrites xs
  }
}

// Rescore write (R16-validated): one block per flagged token; gather winner row.
__global__ __launch_bounds__(256) void svq_rescore_write(const float* __restrict__ emb,
                                                         float* __restrict__ out,
                                                         const unsigned int* __restrict__ ctr,
                                                         const int* __restrict__ list,
                                                         const unsigned long long* __restrict__ tokmin,
                                                         int cap) {
  const int tid = threadIdx.x;
  int n = (int)*ctr;
  if (n > cap) n = cap;
  for (int i = blockIdx.x; i < n; i += gridDim.x) {
    unsigned long long key = tokmin[i];
    if (key == ~0ull) continue;
    const int code = (int)(unsigned int)(key & 0xFFFFFFFFull);
    const int tok = list[i];
    out[(size_t)(tok >> 12) * NDIM * TLEN + (size_t)tid * TLEN + (tok & (TLEN - 1))] =
        emb[(size_t)code * NDIM + tid];
  }
}

extern "C" void kernel_launch(void* const* d_in, const int* in_sizes, int n_in,
                              void* d_out, int out_size, void* d_ws, size_t ws_size,
                              hipStream_t stream) {
  (void)in_sizes; (void)n_in; (void)out_size;
  const float* x   = (const float*)d_in[0];
  const float* emb = (const float*)d_in[1];
  float* out = (float*)d_out;

  // ws: ehi 512K | embT 1M | ctr 16B | tokmin cap*8 | list cap*4 | xcomp cap*1024
  unsigned short*     ehi    = (unsigned short*)d_ws;
  float*              embT   = (float*)((char*)d_ws + (size_t)512 * 1024);
  unsigned int*       ctr    = (unsigned int*)((char*)d_ws + (size_t)1536 * 1024);
  long avail = (long)ws_size - (long)1536 * 1024 - 16;
  int cap = avail > 0 ? (int)(avail / 1040 < 32768 ? avail / 1040 : 32768) : 0;
  unsigned long long* tokmin = (unsigned long long*)((char*)ctr + 16);
  int*                lst    = (int*)((char*)tokmin + (size_t)cap * 8);
  float*              xcomp  = (float*)((char*)lst + (size_t)cap * 4);

  svq_prep_emb<<<dim3(1024), dim3(256), 0, stream>>>(emb, ehi, ctr, tokmin, cap);
  svq_transpose<<<dim3(64), dim3(256), 0, stream>>>(emb, embT);
  svq_main<<<dim3(NBATCH * (TLEN / BT)), dim3(256), 0, stream>>>(
      x, emb, (const short8*)ehi, out, ctr, lst, xcomp, cap);
  svq_rescore_part<<<dim3(2048), dim3(256), 0, stream>>>(xcomp, embT, ctr, tokmin, cap);
  svq_rescore_write<<<dim3(2048), dim3(256), 0, stream>>>(emb, out, ctr, lst, tokmin, cap);
}